// Round 1
// baseline (346.537 us; speedup 1.0000x reference)
//
#include <hip/hip_runtime.h>

typedef unsigned short u16;
typedef __attribute__((ext_vector_type(8))) short bf16x8;
typedef __attribute__((ext_vector_type(4))) float f32x4;

union U8 { unsigned long long u[2]; bf16x8 v; };

#define LEAKY 0.2f
#define LN_EPS 1e-5f

// fp32 -> bf16 round-to-nearest-even (bit pattern)
__device__ __forceinline__ u16 f2bf(float f) {
  union { float f; unsigned int u; } a; a.f = f;
  unsigned int u = a.u;
  unsigned int r = (u + 0x7fffu + ((u >> 16) & 1u)) >> 16;
  return (u16)r;
}

// Convert W1/W2/W3 (fp32, torch [out][in]) into 8 bf16 chunk images in ws:
// chunk image c: [128 rows][68 cols] (K=64 chunk + 4 pad), row-major.
// chunks 0-3: W1 k=0..255; 4-5: W2; 6-7: W3.
__global__ void convert_weights(const float* __restrict__ W1,
                                const float* __restrict__ W2,
                                const float* __restrict__ W3,
                                u16* __restrict__ wout) {
  int id = blockIdx.x * 256 + threadIdx.x;   // 0..65535
  int chunk = id >> 13;
  int r = (id >> 6) & 127;
  int k = id & 63;
  float v;
  if (chunk < 4)      v = W1[r * 256 + chunk * 64 + k];
  else if (chunk < 6) v = W2[r * 128 + (chunk - 4) * 64 + k];
  else                v = W3[r * 128 + (chunk - 6) * 64 + k];
  wout[chunk * 8704 + r * 68 + k] = f2bf(v);
}

// stage one 128x68 bf16 chunk image (17408 B = 1088 uint4) global->LDS
__device__ __forceinline__ void stage_w(const u16* __restrict__ wsrc,
                                        u16* __restrict__ wdst, int tid) {
  const uint4* s = (const uint4*)wsrc;
  uint4* d = (uint4*)wdst;
  #pragma unroll
  for (int i = 0; i < 4; ++i) d[tid + i * 256] = s[tid + i * 256];
  if (tid < 64) d[tid + 1024] = s[tid + 1024];
}

// one K=64 chunk of MFMA: arow = &A[this lane's row][chunk_k_base + 4*lg],
// wb = &wbuf[lr][4*lg]. 16 MFMAs into acc[8].
__device__ __forceinline__ void chunk_mfma(const u16* __restrict__ arow,
                                           const u16* __restrict__ wb,
                                           f32x4* acc) {
  #pragma unroll
  for (int k0 = 0; k0 < 64; k0 += 32) {
    U8 a;
    a.u[0] = *(const unsigned long long*)(arow + k0);
    a.u[1] = *(const unsigned long long*)(arow + k0 + 16);
    #pragma unroll
    for (int n = 0; n < 8; ++n) {
      U8 b;
      const u16* bp = wb + n * 16 * 68 + k0;
      b.u[0] = *(const unsigned long long*)bp;
      b.u[1] = *(const unsigned long long*)(bp + 16);
      acc[n] = __builtin_amdgcn_mfma_f32_16x16x32_bf16(a.v, b.v, acc[n], 0, 0, 0);
    }
  }
}

__global__ __launch_bounds__(256, 2) void edge_mlp(
    const float* __restrict__ x, const int* __restrict__ ei,
    const float* __restrict__ b1, const float* __restrict__ b2,
    const float* __restrict__ gamma, const float* __restrict__ beta,
    const u16* __restrict__ wbf, float* __restrict__ out, int E) {

  // strides padded: 260*2B=520B, 132*2B=264B, 68*2B=136B -> all advance 2
  // banks/row => 64-lane b64 reads are <=2-way (free) bank aliasing.
  __shared__ __align__(16) u16 msg[64][260];    // 33280 B  [edge][256 k]
  __shared__ __align__(16) u16 hbuf[64][132];   // 16896 B  [edge][128 k]
  __shared__ __align__(16) u16 wbuf[128][68];   // 17408 B  [n][64 k]

  const int tid = threadIdx.x;
  const int lane = tid & 63;
  const int wv = tid >> 6;       // wave 0..3 -> rows 16wv..16wv+15
  const int lg = lane >> 4;      // lane group 0..3
  const int lr = lane & 15;      // lane-in-group = col-in-tile / row-in-tile
  const int e0 = blockIdx.x * 64;

  // per-lane LN / bias params: col = 16n + lr
  float b1r[8], b2r[8], gr[8], br[8];
  #pragma unroll
  for (int n = 0; n < 8; ++n) {
    int col = n * 16 + lr;
    b1r[n] = b1[col]; b2r[n] = b2[col]; gr[n] = gamma[col]; br[n] = beta[col];
  }

  // ---- gather: msg[row] = [ x[dest] | x[src] ] as bf16 ----
  {
    const int row = tid >> 2;           // 0..63 (wave w writes its own rows)
    const int part = tid & 3;           // 0,1: dest halves; 2,3: src halves
    const int e = e0 + row;
    // reference: src=edge_index[0], dest=edge_index[1]
    const int node = (part < 2) ? ei[E + e] : ei[e];
    const float* xp = x + node * 128 + (part & 1) * 64;
    u16* mp = &msg[row][part * 64];
    #pragma unroll
    for (int j = 0; j < 64; j += 4) {
      float4 v = *(const float4*)(xp + j);
      unsigned long long pk =
          (unsigned long long)f2bf(v.x) |
          ((unsigned long long)f2bf(v.y) << 16) |
          ((unsigned long long)f2bf(v.z) << 32) |
          ((unsigned long long)f2bf(v.w) << 48);
      *(unsigned long long*)(mp + j) = pk;
    }
  }

  f32x4 acc[8];

  // ---------------- GEMM1: [64,256] @ W1^T -> h1 ----------------
  #pragma unroll
  for (int n = 0; n < 8; ++n) acc[n] = (f32x4)(0.0f);
  for (int c = 0; c < 4; ++c) {
    __syncthreads();
    stage_w(wbf + c * 8704, &wbuf[0][0], tid);
    __syncthreads();
    chunk_mfma(&msg[16 * wv + lr][c * 64 + 4 * lg], &wbuf[lr][4 * lg], acc);
  }
  // bias + leaky -> hbuf (each wave writes only its own rows)
  #pragma unroll
  for (int n = 0; n < 8; ++n) {
    #pragma unroll
    for (int j = 0; j < 4; ++j) {
      float v = acc[n][j] + b1r[n];
      v = (v >= 0.f) ? v : LEAKY * v;
      hbuf[16 * wv + 4 * lg + j][n * 16 + lr] = f2bf(v);
    }
  }

  // ---------------- GEMM2: h1 @ W2^T -> h2 ----------------
  #pragma unroll
  for (int n = 0; n < 8; ++n) acc[n] = (f32x4)(0.0f);
  for (int c = 0; c < 2; ++c) {
    __syncthreads();
    stage_w(wbf + (4 + c) * 8704, &wbuf[0][0], tid);
    __syncthreads();
    chunk_mfma(&hbuf[16 * wv + lr][c * 64 + 4 * lg], &wbuf[lr][4 * lg], acc);
  }
  #pragma unroll
  for (int n = 0; n < 8; ++n) {
    #pragma unroll
    for (int j = 0; j < 4; ++j) {
      float v = acc[n][j] + b2r[n];
      v = (v >= 0.f) ? v : LEAKY * v;
      hbuf[16 * wv + 4 * lg + j][n * 16 + lr] = f2bf(v);
    }
  }

  // ---------------- GEMM3: h2 @ W3^T -> h3 (fp32 in acc) ----------------
  #pragma unroll
  for (int n = 0; n < 8; ++n) acc[n] = (f32x4)(0.0f);
  for (int c = 0; c < 2; ++c) {
    __syncthreads();
    stage_w(wbf + (6 + c) * 8704, &wbuf[0][0], tid);
    __syncthreads();
    chunk_mfma(&hbuf[16 * wv + lr][c * 64 + 4 * lg], &wbuf[lr][4 * lg], acc);
  }

  // ---------------- LayerNorm per row + store ----------------
  // acc[n][j]: row = 16wv + 4lg + j, col = 16n + lr. Row lives in the 16
  // lanes of this lane-group -> reduce with xor masks 1,2,4,8.
  #pragma unroll
  for (int j = 0; j < 4; ++j) {
    float s = 0.f, ss = 0.f;
    #pragma unroll
    for (int n = 0; n < 8; ++n) { float v = acc[n][j]; s += v; ss += v * v; }
    #pragma unroll
    for (int m = 1; m <= 8; m <<= 1) {
      s  += __shfl_xor(s, m, 64);
      ss += __shfl_xor(ss, m, 64);
    }
    float mean = s * (1.f / 128.f);
    float var = ss * (1.f / 128.f) - mean * mean;
    float inv = rsqrtf(var + LN_EPS);
    float* op = out + (long)(e0 + 16 * wv + 4 * lg + j) * 128;
    #pragma unroll
    for (int n = 0; n < 8; ++n) {
      op[n * 16 + lr] = (acc[n][j] - mean) * inv * gr[n] + br[n];
    }
  }
}

extern "C" void kernel_launch(void* const* d_in, const int* in_sizes, int n_in,
                              void* d_out, int out_size, void* d_ws, size_t ws_size,
                              hipStream_t stream) {
  const float* x     = (const float*)d_in[0];
  const int*   ei    = (const int*)d_in[1];
  const float* W1    = (const float*)d_in[2];
  const float* b1    = (const float*)d_in[3];
  const float* W2    = (const float*)d_in[4];
  const float* b2    = (const float*)d_in[5];
  const float* W3    = (const float*)d_in[6];
  const float* gamma = (const float*)d_in[7];
  const float* beta  = (const float*)d_in[8];
  const int E = in_sizes[1] / 2;   // 640000
  u16* wbf = (u16*)d_ws;           // 139264 B of ws used

  convert_weights<<<256, 256, 0, stream>>>(W1, W2, W3, wbf);
  edge_mlp<<<E / 64, 256, 0, stream>>>(x, ei, b1, b2, gamma, beta, wbf,
                                       (float*)d_out, E);
}